// Round 8
// baseline (140.849 us; speedup 1.0000x reference)
//
#include <hip/hip_runtime.h>

// SmallSMBlock: K = Conv2d(1,9,3,'same')(image)+b per pixel; y[b] = 9-tap apply to x[b].
// R2 (LDS+barriers), R6 (barrier-free 32x32), R7 (512x8 row tiles) ALL ~19 us/dispatch
// vs ~11 us compulsory-traffic floor; even a cache-warm second launch costs ~19 us.
// Models falsified; kernel counters are invisible (top-5 = 42-us harness poison fills).
// R8 = VISIBILITY PROBE: gridDim.z = 3, every z-slice computes the IDENTICAL full
// output (racing stores write byte-identical values -> benign; result unchanged).
// At ~3x duration the kernel becomes the top dispatch and exposes hbm_gbps /
// FETCH / WRITE / VALUBusy / Occupancy to diagnose BW-bound vs latency-bound.

#define H  1024
#define W  1024
#define NB 8
#define HW ((size_t)H * (size_t)W)

__global__ __launch_bounds__(256)
void smblock_kernel(const float* __restrict__ image,
                    const float* __restrict__ x,
                    const float* __restrict__ kw,   // (9,1,3,3)
                    const float* __restrict__ kb,   // (9,)
                    float* __restrict__ y)          // (8,1,H,W)
{
    // blockIdx.z intentionally unused: z-slices duplicate the same work (probe).
    const int tid = threadIdx.x;
    const int r   = tid >> 3;                    // pixel row in 32x32 tile
    const int cg  = tid & 7;                     // col group (4 adjacent cols)
    const int h   = (int)blockIdx.y * 32 + r;
    const int w   = (int)blockIdx.x * 32 + 4 * cg;

    // ---- row-clamped 32-bit offsets + border masks (branchless) ----
    unsigned o4[3], ol[3], orr[3];
    float mc[3], mlm[3], mrm[3];
    {
        const bool lv = (w >= 1);
        const bool rv = (w + 4 < W);
        #pragma unroll
        for (int a = 0; a < 3; ++a) {
            int hh = h + a - 1;
            int hc = hh < 0 ? 0 : (hh > H - 1 ? H - 1 : hh);
            unsigned ro = (unsigned)hc * W;
            o4[a]  = ro + w;
            ol[a]  = ro + (lv ? (w - 1) : w);
            orr[a] = ro + (rv ? (w + 4) : w);
            float hv = ((unsigned)hh < (unsigned)H) ? 1.f : 0.f;
            mc[a]  = hv;
            mlm[a] = lv ? hv : 0.f;
            mrm[a] = rv ? hv : 0.f;
        }
    }

    // ---- issue batch-0 x loads immediately ----
    float nxt[18];
    #pragma unroll
    for (int a = 0; a < 3; ++a) {
        float4 f = *(const float4*)(x + o4[a]);
        nxt[6*a+0] = x[ol[a]];
        nxt[6*a+1] = f.x; nxt[6*a+2] = f.y; nxt[6*a+3] = f.z; nxt[6*a+4] = f.w;
        nxt[6*a+5] = x[orr[a]];
    }

    // ---- per-pixel predicted kernels K[j][t] for pixels (h, w+j) ----
    float K[4][9];
    #pragma unroll
    for (int t = 0; t < 9; ++t) {
        float bt = kb[t];
        #pragma unroll
        for (int j = 0; j < 4; ++j) K[j][t] = bt;
    }
    #pragma unroll
    for (int a = 0; a < 3; ++a) {
        float4 f = *(const float4*)(image + o4[a]);
        float vl = image[ol[a]] * mlm[a];
        float vr = image[orr[a]] * mrm[a];
        float v[6] = { vl, f.x*mc[a], f.y*mc[a], f.z*mc[a], f.w*mc[a], vr };
        #pragma unroll
        for (int d = 0; d < 3; ++d)
            #pragma unroll
            for (int t = 0; t < 9; ++t) {
                float wgt = kw[t * 9 + 3 * a + d];
                #pragma unroll
                for (int j = 0; j < 4; ++j)
                    K[j][t] += wgt * v[j + d];
            }
    }

    // ---- batch loop: depth-1 register pipeline, zero barriers ----
    float cur[18];
    #pragma unroll 1
    for (int b = 0; b < NB; ++b) {
        #pragma unroll
        for (int a = 0; a < 3; ++a) {
            cur[6*a+0] = nxt[6*a+0] * mlm[a];
            cur[6*a+1] = nxt[6*a+1] * mc[a];
            cur[6*a+2] = nxt[6*a+2] * mc[a];
            cur[6*a+3] = nxt[6*a+3] * mc[a];
            cur[6*a+4] = nxt[6*a+4] * mc[a];
            cur[6*a+5] = nxt[6*a+5] * mrm[a];
        }
        if (b + 1 < NB) {
            const float* xb = x + (size_t)(b + 1) * HW;
            #pragma unroll
            for (int a = 0; a < 3; ++a) {
                float4 f = *(const float4*)(xb + o4[a]);
                nxt[6*a+0] = xb[ol[a]];
                nxt[6*a+1] = f.x; nxt[6*a+2] = f.y; nxt[6*a+3] = f.z; nxt[6*a+4] = f.w;
                nxt[6*a+5] = xb[orr[a]];
            }
        }
        float a0 = 0.f, a1 = 0.f, a2 = 0.f, a3 = 0.f;
        #pragma unroll
        for (int a = 0; a < 3; ++a)
            #pragma unroll
            for (int d = 0; d < 3; ++d) {
                a0 += cur[6*a + 0 + d] * K[0][3*a+d];
                a1 += cur[6*a + 1 + d] * K[1][3*a+d];
                a2 += cur[6*a + 2 + d] * K[2][3*a+d];
                a3 += cur[6*a + 3 + d] * K[3][3*a+d];
            }
        float4 o; o.x = a0; o.y = a1; o.z = a2; o.w = a3;
        *(float4*)(y + (size_t)b * HW + (size_t)((unsigned)h * W + w)) = o;
    }
}

extern "C" void kernel_launch(void* const* d_in, const int* in_sizes, int n_in,
                              void* d_out, int out_size, void* d_ws, size_t ws_size,
                              hipStream_t stream)
{
    const float* image = (const float*)d_in[0];  // (1,1024,1024)
    const float* x     = (const float*)d_in[1];  // (8,1,1024,1024)
    const float* kw    = (const float*)d_in[2];  // (9,1,3,3)
    const float* kb    = (const float*)d_in[3];  // (9,)
    float* y = (float*)d_out;                    // (8,1,1024,1024)

    // PROBE: z=3 -> 3x identical work in ONE dispatch so the kernel outranks the
    // 42-us harness fills in the rocprof top-5 and exposes its counters.
    dim3 grid(W / 32, H / 32, 3);
    smblock_kernel<<<grid, 256, 0, stream>>>(image, x, kw, kb, y);
}

// Round 9
// 102.911 us; speedup vs baseline: 1.3687x; 1.3687x over previous
//
#include <hip/hip_runtime.h>

// SmallSMBlock: K = Conv2d(1,9,3,'same')(image)+b per pixel; y[b] = 9-tap apply to x[b].
// R8 probe (z=3) exposed counters: FETCH 54.4 MB/launch-equiv (vs ~38 ideal), 3.9 TB/s,
// VALU 30% -> limiter is per-XCD L2 FILL traffic: round-robin dispatch puts stencil
// neighbors on different XCDs, so every x line is filled into up to 5 XCD L2s
// (owner + 4 halo neighbors); non-coherent L2s can't share, L3 doesn't absorb fills.
// R9: XCD BAND SWIZZLE - bid&7 (the XCD under round-robin mapping) selects a
// contiguous 128-row band; all halo sharing becomes XCD-local (512 KB/batch band
// slice << 4 MB L2). Duplicate fills only at 7 band-boundary rows.

#define H  1024
#define W  1024
#define NB 8
#define HW ((size_t)H * (size_t)W)

__global__ __launch_bounds__(256)
void smblock_kernel(const float* __restrict__ image,
                    const float* __restrict__ x,
                    const float* __restrict__ kw,   // (9,1,3,3)
                    const float* __restrict__ kb,   // (9,)
                    float* __restrict__ y)          // (8,1,H,W)
{
    // ---- XCD band swizzle: bid&7 = XCD (round-robin heuristic) -> 128-row band ----
    const int bid = (int)blockIdx.x;           // 0..1023
    const int xcd = bid & 7;                   // band id
    const int idx = bid >> 3;                  // 0..127 within band
    const int ty  = idx >> 5;                  // 0..3 tile-row in band
    const int tx  = idx & 31;                  // 0..31 tile-col

    const int tid = threadIdx.x;
    const int r   = tid >> 3;                    // pixel row in 32x32 tile
    const int cg  = tid & 7;                     // col group (4 adjacent cols)
    const int h   = (xcd << 7) + (ty << 5) + r;
    const int w   = (tx << 5) + 4 * cg;

    // ---- row-clamped 32-bit offsets + border masks (branchless) ----
    unsigned o4[3], ol[3], orr[3];
    float mc[3], mlm[3], mrm[3];
    {
        const bool lv = (w >= 1);
        const bool rv = (w + 4 < W);
        #pragma unroll
        for (int a = 0; a < 3; ++a) {
            int hh = h + a - 1;
            int hc = hh < 0 ? 0 : (hh > H - 1 ? H - 1 : hh);
            unsigned ro = (unsigned)hc * W;
            o4[a]  = ro + w;
            ol[a]  = ro + (lv ? (w - 1) : w);
            orr[a] = ro + (rv ? (w + 4) : w);
            float hv = ((unsigned)hh < (unsigned)H) ? 1.f : 0.f;
            mc[a]  = hv;
            mlm[a] = lv ? hv : 0.f;
            mrm[a] = rv ? hv : 0.f;
        }
    }

    // ---- issue batch-0 x loads immediately ----
    float nxt[18];
    #pragma unroll
    for (int a = 0; a < 3; ++a) {
        float4 f = *(const float4*)(x + o4[a]);
        nxt[6*a+0] = x[ol[a]];
        nxt[6*a+1] = f.x; nxt[6*a+2] = f.y; nxt[6*a+3] = f.z; nxt[6*a+4] = f.w;
        nxt[6*a+5] = x[orr[a]];
    }

    // ---- per-pixel predicted kernels K[j][t] for pixels (h, w+j) ----
    float K[4][9];
    #pragma unroll
    for (int t = 0; t < 9; ++t) {
        float bt = kb[t];
        #pragma unroll
        for (int j = 0; j < 4; ++j) K[j][t] = bt;
    }
    #pragma unroll
    for (int a = 0; a < 3; ++a) {
        float4 f = *(const float4*)(image + o4[a]);
        float vl = image[ol[a]] * mlm[a];
        float vr = image[orr[a]] * mrm[a];
        float v[6] = { vl, f.x*mc[a], f.y*mc[a], f.z*mc[a], f.w*mc[a], vr };
        #pragma unroll
        for (int d = 0; d < 3; ++d)
            #pragma unroll
            for (int t = 0; t < 9; ++t) {
                float wgt = kw[t * 9 + 3 * a + d];
                #pragma unroll
                for (int j = 0; j < 4; ++j)
                    K[j][t] += wgt * v[j + d];
            }
    }

    // ---- batch loop: depth-1 register pipeline, zero barriers ----
    float cur[18];
    #pragma unroll 1
    for (int b = 0; b < NB; ++b) {
        #pragma unroll
        for (int a = 0; a < 3; ++a) {
            cur[6*a+0] = nxt[6*a+0] * mlm[a];
            cur[6*a+1] = nxt[6*a+1] * mc[a];
            cur[6*a+2] = nxt[6*a+2] * mc[a];
            cur[6*a+3] = nxt[6*a+3] * mc[a];
            cur[6*a+4] = nxt[6*a+4] * mc[a];
            cur[6*a+5] = nxt[6*a+5] * mrm[a];
        }
        if (b + 1 < NB) {
            const float* xb = x + (size_t)(b + 1) * HW;
            #pragma unroll
            for (int a = 0; a < 3; ++a) {
                float4 f = *(const float4*)(xb + o4[a]);
                nxt[6*a+0] = xb[ol[a]];
                nxt[6*a+1] = f.x; nxt[6*a+2] = f.y; nxt[6*a+3] = f.z; nxt[6*a+4] = f.w;
                nxt[6*a+5] = xb[orr[a]];
            }
        }
        float a0 = 0.f, a1 = 0.f, a2 = 0.f, a3 = 0.f;
        #pragma unroll
        for (int a = 0; a < 3; ++a)
            #pragma unroll
            for (int d = 0; d < 3; ++d) {
                a0 += cur[6*a + 0 + d] * K[0][3*a+d];
                a1 += cur[6*a + 1 + d] * K[1][3*a+d];
                a2 += cur[6*a + 2 + d] * K[2][3*a+d];
                a3 += cur[6*a + 3 + d] * K[3][3*a+d];
            }
        float4 o; o.x = a0; o.y = a1; o.z = a2; o.w = a3;
        *(float4*)(y + (size_t)b * HW + (size_t)((unsigned)h * W + w)) = o;
    }
}

extern "C" void kernel_launch(void* const* d_in, const int* in_sizes, int n_in,
                              void* d_out, int out_size, void* d_ws, size_t ws_size,
                              hipStream_t stream)
{
    const float* image = (const float*)d_in[0];  // (1,1024,1024)
    const float* x     = (const float*)d_in[1];  // (8,1,1024,1024)
    const float* kw    = (const float*)d_in[2];  // (9,1,3,3)
    const float* kb    = (const float*)d_in[3];  // (9,)
    float* y = (float*)d_out;                    // (8,1,1024,1024)

    smblock_kernel<<<dim3(1024), 256, 0, stream>>>(image, x, kw, kb, y);
}